// Round 2
// baseline (825.117 us; speedup 1.0000x reference)
//
#include <hip/hip_runtime.h>
#include <cstdint>

#define DF 128

typedef float f32x4 __attribute__((ext_vector_type(4)));
typedef short bf16x8 __attribute__((ext_vector_type(8)));

__device__ __forceinline__ unsigned short f2bf(float f) {
  unsigned int u = __float_as_uint(f);
  unsigned int r = (u + 0x7fffu + ((u >> 16) & 1u)) >> 16;
  return (unsigned short)r;
}

__device__ __forceinline__ unsigned int pack2(float lo, float hi) {
  return (unsigned int)f2bf(lo) | ((unsigned int)f2bf(hi) << 16);
}

// ---- W concat+convert: wbf[c][k] bf16, k<128 -> Wl[c][k], k>=128 -> Wr[c][k-128]
__global__ void k_wcvt(const float* __restrict__ Wl, const float* __restrict__ Wr,
                       unsigned short* __restrict__ wbf) {
  int i = blockIdx.x * 256 + threadIdx.x;  // 0..32767
  int c = i >> 8;
  int k = i & 255;
  float v = (k < DF) ? Wl[c * DF + k] : Wr[c * DF + (k - DF)];
  wbf[i] = f2bf(v);
}

// ---- degree count
__global__ void k_deg(const int* __restrict__ ei, int* __restrict__ deg, int E) {
  int e = blockIdx.x * 256 + threadIdx.x;
  if (e < E) atomicAdd(&deg[ei[(size_t)E + e]], 1);
}

// ---- bucket offsets (order-free disjoint buckets via one atomic counter)
__global__ void k_off(const int* __restrict__ deg, int* __restrict__ start,
                      int* __restrict__ cursor, int* __restrict__ total, int n) {
  int i = blockIdx.x * 256 + threadIdx.x;
  if (i < n) {
    int d = deg[i];
    int p = atomicAdd(total, d);
    start[i] = p;
    cursor[i] = p;
  }
}

// ---- CSR fill
__global__ void k_fill(const int* __restrict__ ei, int* __restrict__ cursor,
                       int* __restrict__ adj, int E) {
  int e = blockIdx.x * 256 + threadIdx.x;
  if (e < E) {
    int s = ei[e];
    int t = ei[(size_t)E + e];
    int p = atomicAdd(&cursor[t], 1);
    adj[p] = s;
  }
}

// ---- mean aggregation: one wave per node, 2 features per lane, bf16 output
__global__ void k_agg(const float* __restrict__ x, const int* __restrict__ start,
                      const int* __restrict__ deg, const int* __restrict__ adj,
                      unsigned short* __restrict__ aggbf, int n) {
  int node = blockIdx.x * 4 + (threadIdx.x >> 6);
  if (node >= n) return;
  int lane = threadIdx.x & 63;
  const float2* x2 = (const float2*)x;
  int rs = start[node];
  int d = deg[node];
  float s0 = 0.f, s1 = 0.f;
  for (int j = 0; j < d; ++j) {
    int src = adj[rs + j];
    float2 v = x2[(size_t)src * 64 + lane];
    s0 += v.x;
    s1 += v.y;
  }
  float inv = 1.0f / (float)(d > 1 ? d : 1);
  *(unsigned int*)(aggbf + (size_t)node * DF + lane * 2) = pack2(s0 * inv, s1 * inv);
}

// ---- fused GEMM (h = [agg|x] @ [Wl|Wr]^T + bl) + row L2 norm + feature sums
__global__ __launch_bounds__(256) void k_gemm(
    const unsigned short* __restrict__ aggbf, const float* __restrict__ x,
    const unsigned short* __restrict__ wbf, const float* __restrict__ bl,
    float* __restrict__ hout, float* __restrict__ fsum, float* __restrict__ fsq, int n) {
  __shared__ __align__(16) unsigned short Abuf[64 * 128];   // 16 KB (one K-half)
  __shared__ __align__(16) unsigned short Bbuf[128 * 128];  // 32 KB
  int tid = threadIdx.x;
  int node0 = blockIdx.x * 64;
  int wv = tid >> 6, lane = tid & 63;
  int lo = lane & 15, hi = lane >> 4;

  f32x4 acc[8] = {};

  int arow = wv * 16 + lo;
  int abase = arow * 256 + hi * 16;  // byte offset in Abuf
  int aswz = (arow & 7) << 4;

  for (int ph = 0; ph < 2; ++ph) {
    if (ph) __syncthreads();
    // stage A half-tile: 64 rows x 128 k (bf16, XOR-swizzled)
    if (ph == 0) {
#pragma unroll
      for (int it = 0; it < 4; ++it) {
        int id = it * 256 + tid;           // 0..1023
        int row = id >> 4;                 // 0..63
        int inner = (id & 15) * 16;        // byte in row, 0..255
        uint4 v = make_uint4(0u, 0u, 0u, 0u);
        int gr = node0 + row;
        if (gr < n) v = *(const uint4*)(aggbf + (size_t)gr * DF + inner / 2);
        *(uint4*)((char*)Abuf + ((row * 256 + inner) ^ ((row & 7) << 4))) = v;
      }
    } else {
#pragma unroll
      for (int it = 0; it < 4; ++it) {
        int id = it * 256 + tid;
        int row = id >> 4;
        int inner = (id & 15) * 16;
        int e0 = inner / 2;                // fp32 element index 0..127 step 8
        uint4 v = make_uint4(0u, 0u, 0u, 0u);
        int gr = node0 + row;
        if (gr < n) {
          const float4* xr = (const float4*)(x + (size_t)gr * DF + e0);
          float4 a = xr[0], b = xr[1];
          v.x = pack2(a.x, a.y);
          v.y = pack2(a.z, a.w);
          v.z = pack2(b.x, b.y);
          v.w = pack2(b.z, b.w);
        }
        *(uint4*)((char*)Abuf + ((row * 256 + inner) ^ ((row & 7) << 4))) = v;
      }
    }
    // stage B half-tile: 128 cols x 128 k
#pragma unroll
    for (int it = 0; it < 8; ++it) {
      int id = it * 256 + tid;             // 0..2047
      int c = id >> 4;                     // 0..127
      int inner = (id & 15) * 16;
      uint4 v = *(const uint4*)((const char*)wbf + (size_t)c * 512 + ph * 256 + inner);
      *(uint4*)((char*)Bbuf + ((c * 256 + inner) ^ ((c & 7) << 4))) = v;
    }
    __syncthreads();
#pragma unroll
    for (int kk = 0; kk < 4; ++kk) {
      bf16x8 af = *(const bf16x8*)((const char*)Abuf + ((abase + kk * 64) ^ aswz));
#pragma unroll
      for (int f = 0; f < 8; ++f) {
        int brow = f * 16 + lo;
        int bb = (brow * 256 + hi * 16 + kk * 64) ^ ((brow & 7) << 4);
        bf16x8 bfr = *(const bf16x8*)((const char*)Bbuf + bb);
        acc[f] = __builtin_amdgcn_mfma_f32_16x16x32_bf16(af, bfr, acc[f], 0, 0, 0);
      }
    }
  }

  // ---- epilogue: bias, guard pad rows, row L2 norm, store h, feature sums
  int r0 = node0 + wv * 16 + hi * 4;  // first of this thread's 4 rows
#pragma unroll
  for (int f = 0; f < 8; ++f) {
    float b = bl[f * 16 + lo];
#pragma unroll
    for (int r = 0; r < 4; ++r) acc[f][r] += b;
  }
#pragma unroll
  for (int r = 0; r < 4; ++r) {
    if (r0 + r >= n) {
#pragma unroll
      for (int f = 0; f < 8; ++f) acc[f][r] = 0.f;
    }
  }
  float ss[4] = {0.f, 0.f, 0.f, 0.f};
#pragma unroll
  for (int f = 0; f < 8; ++f)
#pragma unroll
    for (int r = 0; r < 4; ++r) ss[r] += acc[f][r] * acc[f][r];
#pragma unroll
  for (int m = 1; m <= 8; m <<= 1) {
#pragma unroll
    for (int r = 0; r < 4; ++r) ss[r] += __shfl_xor(ss[r], m, 64);
  }
#pragma unroll
  for (int r = 0; r < 4; ++r) {
    float inv = 1.0f / fmaxf(sqrtf(ss[r]), 1e-12f);
#pragma unroll
    for (int f = 0; f < 8; ++f) acc[f][r] *= inv;
  }
  float s1[8], s2[8];
#pragma unroll
  for (int f = 0; f < 8; ++f) { s1[f] = 0.f; s2[f] = 0.f; }
#pragma unroll
  for (int f = 0; f < 8; ++f) {
#pragma unroll
    for (int r = 0; r < 4; ++r) {
      float v = acc[f][r];
      s1[f] += v;
      s2[f] += v * v;
      if (r0 + r < n) hout[(size_t)(r0 + r) * DF + f * 16 + lo] = v;
    }
  }
  // reduce feature sums across the 4 hi-groups of the wave
#pragma unroll
  for (int f = 0; f < 8; ++f) {
    s1[f] += __shfl_xor(s1[f], 16, 64);
    s1[f] += __shfl_xor(s1[f], 32, 64);
    s2[f] += __shfl_xor(s2[f], 16, 64);
    s2[f] += __shfl_xor(s2[f], 32, 64);
  }
  if (hi == 0) {
#pragma unroll
    for (int f = 0; f < 8; ++f) {
      atomicAdd(&fsum[f * 16 + lo], s1[f]);
      atomicAdd(&fsq[f * 16 + lo], s2[f]);
    }
  }
}

// ---- GraphNorm coefficients: out = ca*h + cb per feature
__global__ void k_coef(const float* __restrict__ fsum, const float* __restrict__ fsq,
                       const float* __restrict__ gnw, const float* __restrict__ gnb,
                       const float* __restrict__ alpha, float* __restrict__ coef, int n) {
  int j = threadIdx.x;  // 0..127
  float invn = 1.0f / (float)n;
  float mean = fsum[j] * invn;
  float m2 = fsq[j] * invn;
  float a = alpha[j];
  float var = m2 - mean * mean * (2.0f * a - a * a);
  float ca = gnw[j] / sqrtf(var + 1e-5f);
  float cb = gnb[j] - ca * a * mean;
  coef[j] = ca;
  coef[DF + j] = cb;
}

// ---- affine + exact GELU + residual, in-place on d_out
__global__ void k_final(float* __restrict__ out, const float* __restrict__ x,
                        const float* __restrict__ coef, int total4) {
  int i = blockIdx.x * 256 + threadIdx.x;
  if (i >= total4) return;
  int cj = (i & 31) * 4;
  float4 h = ((const float4*)out)[i];
  float4 xv = ((const float4*)x)[i];
  float4 ca = *(const float4*)(coef + cj);
  float4 cb = *(const float4*)(coef + DF + cj);
  float4 o;
#define GEL(comp)                                                         \
  {                                                                       \
    float v = ca.comp * h.comp + cb.comp;                                 \
    float g = 0.5f * v * (1.0f + erff(v * 0.70710678118654752f));         \
    o.comp = g + xv.comp;                                                 \
  }
  GEL(x) GEL(y) GEL(z) GEL(w)
#undef GEL
  ((float4*)out)[i] = o;
}

extern "C" void kernel_launch(void* const* d_in, const int* in_sizes, int n_in,
                              void* d_out, int out_size, void* d_ws, size_t ws_size,
                              hipStream_t stream) {
  const float* x = (const float*)d_in[0];
  const int* ei = (const int*)d_in[1];
  // d_in[2] = batch (all zeros, unused)
  const float* Wl = (const float*)d_in[3];
  const float* bl = (const float*)d_in[4];
  const float* Wr = (const float*)d_in[5];
  const float* gnw = (const float*)d_in[6];
  const float* gnb = (const float*)d_in[7];
  const float* alpha = (const float*)d_in[8];
  int n = in_sizes[2];
  int E = in_sizes[1] / 2;
  float* out = (float*)d_out;
  (void)n_in; (void)out_size; (void)ws_size;

  char* ws = (char*)d_ws;
  // zeroed region: deg[n] | total[1] | fsum[128] | fsq[128]
  int* deg = (int*)ws;
  int* total = (int*)(ws + (size_t)n * 4);
  float* fsum = (float*)(ws + (size_t)(n + 1) * 4);
  float* fsq = (float*)(ws + (size_t)(n + 1 + DF) * 4);
  size_t zbytes = (size_t)(n + 1 + 2 * DF) * 4;
  size_t off = (zbytes + 255) & ~(size_t)255;
  auto carve = [&](size_t b) {
    char* p = ws + off;
    off = (off + b + 255) & ~(size_t)255;
    return p;
  };
  int* start = (int*)carve((size_t)n * 4);
  int* cursor = (int*)carve((size_t)n * 4);
  int* adjv = (int*)carve((size_t)E * 4);
  unsigned short* wbf = (unsigned short*)carve((size_t)DF * 256 * 2);
  float* coef = (float*)carve(256 * 4);
  unsigned short* aggbf = (unsigned short*)carve((size_t)n * DF * 2);

  hipMemsetAsync(ws, 0, zbytes, stream);
  k_wcvt<<<(DF * 256) / 256, 256, 0, stream>>>(Wl, Wr, wbf);
  k_deg<<<(E + 255) / 256, 256, 0, stream>>>(ei, deg, E);
  k_off<<<(n + 255) / 256, 256, 0, stream>>>(deg, start, cursor, total, n);
  k_fill<<<(E + 255) / 256, 256, 0, stream>>>(ei, cursor, adjv, E);
  k_agg<<<(n + 3) / 4, 256, 0, stream>>>(x, start, deg, adjv, aggbf, n);
  k_gemm<<<(n + 63) / 64, 256, 0, stream>>>(aggbf, x, wbf, bl, out, fsum, fsq, n);
  k_coef<<<1, DF, 0, stream>>>(fsum, fsq, gnw, gnb, alpha, coef, n);
  k_final<<<(n * (DF / 4) + 255) / 256, 256, 0, stream>>>(out, x, coef, n * (DF / 4));
}

// Round 4
// 470.697 us; speedup vs baseline: 1.7530x; 1.7530x over previous
//
#include <hip/hip_runtime.h>
#include <cstdint>

#define DF 128

typedef float f32x4 __attribute__((ext_vector_type(4)));
typedef short bf16x8 __attribute__((ext_vector_type(8)));

__device__ __forceinline__ unsigned short f2bf(float f) {
  unsigned int u = __float_as_uint(f);
  return (unsigned short)((u + 0x7fffu + ((u >> 16) & 1u)) >> 16);
}
__device__ __forceinline__ unsigned int pack2(float lo, float hi) {
  return (unsigned int)f2bf(lo) | ((unsigned int)f2bf(hi) << 16);
}
__device__ __forceinline__ float bflo(unsigned int u) { return __uint_as_float(u << 16); }
__device__ __forceinline__ float bfhi(unsigned int u) { return __uint_as_float(u & 0xffff0000u); }

// ---- W concat+convert: wbf[c][k] bf16, k<128 -> Wl[c][k], k>=128 -> Wr[c][k-128]
__global__ void k_wcvt(const float* __restrict__ Wl, const float* __restrict__ Wr,
                       unsigned short* __restrict__ wbf) {
  int i = blockIdx.x * 256 + threadIdx.x;  // 0..32767
  int c = i >> 8;
  int k = i & 255;
  float v = (k < DF) ? Wl[c * DF + k] : Wr[c * DF + (k - DF)];
  wbf[i] = f2bf(v);
}

// ---- x -> bf16 copy (8 elems/thread)
__global__ void k_xcvt(const float* __restrict__ x, unsigned int* __restrict__ xbf, int total8) {
  int i = blockIdx.x * 256 + threadIdx.x;
  if (i >= total8) return;
  const float4* xr = (const float4*)(x + (size_t)i * 8);
  float4 a = xr[0], b = xr[1];
  uint4 v;
  v.x = pack2(a.x, a.y);
  v.y = pack2(a.z, a.w);
  v.z = pack2(b.x, b.y);
  v.w = pack2(b.z, b.w);
  ((uint4*)xbf)[i] = v;
}

// ---- degree count
__global__ void k_deg(const int* __restrict__ ei, int* __restrict__ deg, int E) {
  int e = blockIdx.x * 256 + threadIdx.x;
  if (e < E) atomicAdd(&deg[ei[(size_t)E + e]], 1);
}

// ---- bucket offsets (order-free disjoint buckets via one atomic counter)
__global__ void k_off(const int* __restrict__ deg, int* __restrict__ start,
                      int* __restrict__ cursor, int* __restrict__ total, int n) {
  int i = blockIdx.x * 256 + threadIdx.x;
  if (i < n) {
    int d = deg[i];
    int p = atomicAdd(total, d);
    start[i] = p;
    cursor[i] = p;
  }
}

// ---- CSR fill
__global__ void k_fill(const int* __restrict__ ei, int* __restrict__ cursor,
                       int* __restrict__ adj, int E) {
  int e = blockIdx.x * 256 + threadIdx.x;
  if (e < E) {
    int s = ei[e];
    int t = ei[(size_t)E + e];
    int p = atomicAdd(&cursor[t], 1);
    adj[p] = s;
  }
}

// ---- mean aggregation: one wave per node, 2 features per lane, bf16 output
template <int BF>
__global__ void k_agg(const float* __restrict__ xf, const unsigned int* __restrict__ xb,
                      const int* __restrict__ start, const int* __restrict__ deg,
                      const int* __restrict__ adj, unsigned short* __restrict__ aggbf, int n) {
  int node = blockIdx.x * 4 + (threadIdx.x >> 6);
  if (node >= n) return;
  int lane = threadIdx.x & 63;
  int rs = start[node];
  int d = deg[node];
  float s0 = 0.f, s1 = 0.f;
  int j = 0;
  for (; j + 4 <= d; j += 4) {
    int i0 = adj[rs + j], i1 = adj[rs + j + 1], i2 = adj[rs + j + 2], i3 = adj[rs + j + 3];
    if (BF) {
      unsigned int u0 = xb[(size_t)i0 * 64 + lane], u1 = xb[(size_t)i1 * 64 + lane],
                   u2 = xb[(size_t)i2 * 64 + lane], u3 = xb[(size_t)i3 * 64 + lane];
      s0 += bflo(u0) + bflo(u1) + bflo(u2) + bflo(u3);
      s1 += bfhi(u0) + bfhi(u1) + bfhi(u2) + bfhi(u3);
    } else {
      const float2* x2 = (const float2*)xf;
      float2 v0 = x2[(size_t)i0 * 64 + lane], v1 = x2[(size_t)i1 * 64 + lane],
             v2 = x2[(size_t)i2 * 64 + lane], v3 = x2[(size_t)i3 * 64 + lane];
      s0 += v0.x + v1.x + v2.x + v3.x;
      s1 += v0.y + v1.y + v2.y + v3.y;
    }
  }
  for (; j < d; ++j) {
    int i0 = adj[rs + j];
    if (BF) {
      unsigned int u0 = xb[(size_t)i0 * 64 + lane];
      s0 += bflo(u0);
      s1 += bfhi(u0);
    } else {
      const float2* x2 = (const float2*)xf;
      float2 v = x2[(size_t)i0 * 64 + lane];
      s0 += v.x;
      s1 += v.y;
    }
  }
  float inv = 1.0f / (float)(d > 1 ? d : 1);
  *(unsigned int*)(aggbf + (size_t)node * DF + lane * 2) = pack2(s0 * inv, s1 * inv);
}

// ---- fused GEMM (h = [agg|x] @ [Wl|Wr]^T + bl) + row L2 norm + per-block partial sums
template <int XBF>
__global__ __launch_bounds__(256) void k_gemm(
    const unsigned short* __restrict__ aggbf, const unsigned short* __restrict__ xbf,
    const float* __restrict__ x, const unsigned short* __restrict__ wbf,
    const float* __restrict__ bl, float* __restrict__ hout,
    float* __restrict__ pf, int n) {
  __shared__ __align__(16) unsigned short Abuf[64 * 128];   // 16 KB (one K-half)
  __shared__ __align__(16) unsigned short Bbuf[128 * 128];  // 32 KB
  int tid = threadIdx.x;
  int node0 = blockIdx.x * 64;
  int wv = tid >> 6, lane = tid & 63;
  int lo = lane & 15, hi = lane >> 4;

  f32x4 acc[8] = {};

  int arow = wv * 16 + lo;
  int abase = arow * 256 + hi * 16;  // byte offset in Abuf
  int aswz = (arow & 7) << 4;

  for (int ph = 0; ph < 2; ++ph) {
    if (ph) __syncthreads();
    // stage A half-tile: 64 rows x 128 k (bf16, XOR-swizzled)
    if (ph == 0 || XBF) {
      const unsigned short* src = ph == 0 ? aggbf : xbf;
#pragma unroll
      for (int it = 0; it < 4; ++it) {
        int id = it * 256 + tid;           // 0..1023
        int row = id >> 4;                 // 0..63
        int inner = (id & 15) * 16;        // byte in row, 0..255
        uint4 v = make_uint4(0u, 0u, 0u, 0u);
        int gr = node0 + row;
        if (gr < n) v = *(const uint4*)(src + (size_t)gr * DF + inner / 2);
        *(uint4*)((char*)Abuf + ((row * 256 + inner) ^ ((row & 7) << 4))) = v;
      }
    } else {
#pragma unroll
      for (int it = 0; it < 4; ++it) {
        int id = it * 256 + tid;
        int row = id >> 4;
        int inner = (id & 15) * 16;
        int e0 = inner / 2;                // fp32 element index 0..127 step 8
        uint4 v = make_uint4(0u, 0u, 0u, 0u);
        int gr = node0 + row;
        if (gr < n) {
          const float4* xr = (const float4*)(x + (size_t)gr * DF + e0);
          float4 a = xr[0], b = xr[1];
          v.x = pack2(a.x, a.y);
          v.y = pack2(a.z, a.w);
          v.z = pack2(b.x, b.y);
          v.w = pack2(b.z, b.w);
        }
        *(uint4*)((char*)Abuf + ((row * 256 + inner) ^ ((row & 7) << 4))) = v;
      }
    }
    // stage B half-tile: 128 cols x 128 k
#pragma unroll
    for (int it = 0; it < 8; ++it) {
      int id = it * 256 + tid;             // 0..2047
      int c = id >> 4;                     // 0..127
      int inner = (id & 15) * 16;
      uint4 v = *(const uint4*)((const char*)wbf + (size_t)c * 512 + ph * 256 + inner);
      *(uint4*)((char*)Bbuf + ((c * 256 + inner) ^ ((c & 7) << 4))) = v;
    }
    __syncthreads();
#pragma unroll
    for (int kk = 0; kk < 4; ++kk) {
      bf16x8 af = *(const bf16x8*)((const char*)Abuf + ((abase + kk * 64) ^ aswz));
#pragma unroll
      for (int f = 0; f < 8; ++f) {
        int brow = f * 16 + lo;
        int bb = (brow * 256 + hi * 16 + kk * 64) ^ ((brow & 7) << 4);
        bf16x8 bfr = *(const bf16x8*)((const char*)Bbuf + bb);
        acc[f] = __builtin_amdgcn_mfma_f32_16x16x32_bf16(af, bfr, acc[f], 0, 0, 0);
      }
    }
  }

  // ---- epilogue: bias, guard pad rows, row L2 norm, store h, feature partials
  int r0 = node0 + wv * 16 + hi * 4;  // first of this thread's 4 rows
#pragma unroll
  for (int f = 0; f < 8; ++f) {
    float b = bl[f * 16 + lo];
#pragma unroll
    for (int r = 0; r < 4; ++r) acc[f][r] += b;
  }
#pragma unroll
  for (int r = 0; r < 4; ++r) {
    if (r0 + r >= n) {
#pragma unroll
      for (int f = 0; f < 8; ++f) acc[f][r] = 0.f;
    }
  }
  float ss[4] = {0.f, 0.f, 0.f, 0.f};
#pragma unroll
  for (int f = 0; f < 8; ++f)
#pragma unroll
    for (int r = 0; r < 4; ++r) ss[r] += acc[f][r] * acc[f][r];
#pragma unroll
  for (int m = 1; m <= 8; m <<= 1) {
#pragma unroll
    for (int r = 0; r < 4; ++r) ss[r] += __shfl_xor(ss[r], m, 64);
  }
#pragma unroll
  for (int r = 0; r < 4; ++r) {
    float inv = 1.0f / fmaxf(sqrtf(ss[r]), 1e-12f);
#pragma unroll
    for (int f = 0; f < 8; ++f) acc[f][r] *= inv;
  }
  float s1[8], s2[8];
#pragma unroll
  for (int f = 0; f < 8; ++f) { s1[f] = 0.f; s2[f] = 0.f; }
#pragma unroll
  for (int f = 0; f < 8; ++f) {
#pragma unroll
    for (int r = 0; r < 4; ++r) {
      float v = acc[f][r];
      s1[f] += v;
      s2[f] += v * v;
      if (r0 + r < n) hout[(size_t)(r0 + r) * DF + f * 16 + lo] = v;
    }
  }
  // wave reduce across hi-groups -> hi==0 lanes hold per-(f,lo) wave totals
#pragma unroll
  for (int f = 0; f < 8; ++f) {
    s1[f] += __shfl_xor(s1[f], 16, 64);
    s1[f] += __shfl_xor(s1[f], 32, 64);
    s2[f] += __shfl_xor(s2[f], 16, 64);
    s2[f] += __shfl_xor(s2[f], 32, 64);
  }
  // cross-wave reduce in LDS (Abuf reused), then one coalesced 1KB partial store
  __syncthreads();                 // all waves done reading Abuf/Bbuf
  float* red = (float*)Abuf;       // 4 waves x 256 floats = 4KB
  if (hi == 0) {
#pragma unroll
    for (int f = 0; f < 8; ++f) {
      red[wv * 256 + f * 16 + lo] = s1[f];
      red[wv * 256 + 128 + f * 16 + lo] = s2[f];
    }
  }
  __syncthreads();
  float v = red[tid] + red[256 + tid] + red[512 + tid] + red[768 + tid];
  pf[(size_t)blockIdx.x * 256 + tid] = v;
}

// ---- first-level partial reduction: 16 blocks x 256 feats (coalesced)
__global__ void k_reduce(const float* __restrict__ pf, float* __restrict__ pf2, int NB) {
  int g = blockIdx.x, t = threadIdx.x;
  int L = (NB + 15) / 16;
  int b0 = g * L, b1 = (b0 + L < NB) ? b0 + L : NB;
  float a = 0.f;
  for (int r = b0; r < b1; ++r) a += pf[(size_t)r * 256 + t];
  pf2[g * 256 + t] = a;
}

// ---- GraphNorm coefficients: out = ca*h + cb per feature
__global__ void k_coef(const float* __restrict__ pf2,
                       const float* __restrict__ gnw, const float* __restrict__ gnb,
                       const float* __restrict__ alpha, float* __restrict__ coef, int n) {
  int j = threadIdx.x;  // 0..127
  float s = 0.f, q = 0.f;
#pragma unroll
  for (int g = 0; g < 16; ++g) {
    s += pf2[g * 256 + j];
    q += pf2[g * 256 + 128 + j];
  }
  float invn = 1.0f / (float)n;
  float mean = s * invn;
  float m2 = q * invn;
  float a = alpha[j];
  float var = m2 - mean * mean * (2.0f * a - a * a);
  float ca = gnw[j] / sqrtf(var + 1e-5f);
  float cb = gnb[j] - ca * a * mean;
  coef[j] = ca;
  coef[DF + j] = cb;
}

// ---- affine + exact GELU + residual, in-place on d_out
__global__ void k_final(float* __restrict__ out, const float* __restrict__ x,
                        const float* __restrict__ coef, int total4) {
  int i = blockIdx.x * 256 + threadIdx.x;
  if (i >= total4) return;
  int cj = (i & 31) * 4;
  float4 h = ((const float4*)out)[i];
  float4 xv = ((const float4*)x)[i];
  float4 ca = *(const float4*)(coef + cj);
  float4 cb = *(const float4*)(coef + DF + cj);
  float4 o;
#define GEL(comp)                                                         \
  {                                                                       \
    float v = ca.comp * h.comp + cb.comp;                                 \
    float g = 0.5f * v * (1.0f + erff(v * 0.70710678118654752f));         \
    o.comp = g + xv.comp;                                                 \
  }
  GEL(x) GEL(y) GEL(z) GEL(w)
#undef GEL
  ((float4*)out)[i] = o;
}

extern "C" void kernel_launch(void* const* d_in, const int* in_sizes, int n_in,
                              void* d_out, int out_size, void* d_ws, size_t ws_size,
                              hipStream_t stream) {
  const float* x = (const float*)d_in[0];
  const int* ei = (const int*)d_in[1];
  // d_in[2] = batch (all zeros, unused)
  const float* Wl = (const float*)d_in[3];
  const float* bl = (const float*)d_in[4];
  const float* Wr = (const float*)d_in[5];
  const float* gnw = (const float*)d_in[6];
  const float* gnb = (const float*)d_in[7];
  const float* alpha = (const float*)d_in[8];
  int n = in_sizes[2];
  int E = in_sizes[1] / 2;
  int NB = (n + 63) / 64;
  float* out = (float*)d_out;
  (void)n_in; (void)out_size;

  char* ws = (char*)d_ws;
  // zeroed region: deg[n] | total[1]
  int* deg = (int*)ws;
  int* total = (int*)(ws + (size_t)n * 4);
  size_t zbytes = (size_t)(n + 1) * 4;
  size_t off = (zbytes + 255) & ~(size_t)255;
  auto carve = [&](size_t b) {
    char* p = ws + off;
    off = (off + b + 255) & ~(size_t)255;
    return p;
  };
  int* start = (int*)carve((size_t)n * 4);
  int* cursor = (int*)carve((size_t)n * 4);
  int* adjv = (int*)carve((size_t)E * 4);
  unsigned short* wbf = (unsigned short*)carve((size_t)DF * 256 * 2);
  float* coef = (float*)carve(256 * 4);
  float* pf = (float*)carve((size_t)NB * 256 * 4);
  float* pf2 = (float*)carve(16 * 256 * 4);
  unsigned short* aggbf = (unsigned short*)carve((size_t)n * DF * 2);
  size_t need_bf = off + (size_t)n * DF * 2;  // + xbf
  int useBF = (ws_size >= need_bf) ? 1 : 0;
  unsigned int* xbf = (unsigned int*)carve((size_t)n * DF * 2);

  hipMemsetAsync(ws, 0, zbytes, stream);
  k_wcvt<<<(DF * 256) / 256, 256, 0, stream>>>(Wl, Wr, wbf);
  k_deg<<<(E + 255) / 256, 256, 0, stream>>>(ei, deg, E);
  k_off<<<(n + 255) / 256, 256, 0, stream>>>(deg, start, cursor, total, n);
  k_fill<<<(E + 255) / 256, 256, 0, stream>>>(ei, cursor, adjv, E);
  if (useBF) {
    k_xcvt<<<(n * 16 + 255) / 256, 256, 0, stream>>>(x, xbf, n * 16);
    k_agg<1><<<(n + 3) / 4, 256, 0, stream>>>(x, xbf, start, deg, adjv, aggbf, n);
    k_gemm<1><<<NB, 256, 0, stream>>>(aggbf, (const unsigned short*)xbf, x, wbf, bl, out, pf, n);
  } else {
    k_agg<0><<<(n + 3) / 4, 256, 0, stream>>>(x, xbf, start, deg, adjv, aggbf, n);
    k_gemm<0><<<NB, 256, 0, stream>>>(aggbf, (const unsigned short*)xbf, x, wbf, bl, out, pf, n);
  }
  k_reduce<<<16, 256, 0, stream>>>(pf, pf2, NB);
  k_coef<<<1, DF, 0, stream>>>(pf2, gnw, gnb, alpha, coef, n);
  k_final<<<(n * (DF / 4) + 255) / 256, 256, 0, stream>>>(out, x, coef, n * (DF / 4));
}